// Round 1
// baseline (9.373 us; speedup 1.0000x reference)
//
#include <hip/hip_runtime.h>

static constexpr int J  = 17;
static constexpr int NH = 30;

__global__ __launch_bounds__(128) void ae_loss_kernel(
    const float* __restrict__ tm0,   // (B, J, 256, 256)
    const float* __restrict__ tm1,   // (B, J, 512, 512)
    const int*   __restrict__ kps0,  // (B, NH, 3*J)
    const int*   __restrict__ kps1,  // (B, NH, 3*J)
    float*       __restrict__ out)   // (B,)
{
    const int b    = blockIdx.x;
    const int wave = threadIdx.x >> 6;   // 0 -> map0 (res 256), 1 -> map1 (res 512)
    const int lane = threadIdx.x & 63;

    const int    res  = wave ? 512 : 256;
    const float* tmap = wave ? (tm1 + (size_t)b * J * 512 * 512)
                             : (tm0 + (size_t)b * J * 256 * 256);
    const int*   kps  = (wave ? kps1 : kps0) + b * NH * 3 * J;

    __shared__ float s_avg[2][NH];
    __shared__ float s_loss[2];

    float    vals[J];
    unsigned mbits = 0;
    float    avg   = 0.f;
    int      cnt   = 0;

    if (lane < NH) {
        const int* k = kps + lane * 3 * J;
        float sum = 0.f;
        #pragma unroll
        for (int j = 0; j < J; ++j) {
            const int x = k[3 * j + 0];
            const int y = k[3 * j + 1];
            const int v = k[3 * j + 2];
            const float val = tmap[((size_t)j * res + x) * res + y];
            vals[j] = val;
            if (v != 0) { mbits |= (1u << j); cnt++; sum += val; }
        }
        avg = (cnt > 0) ? (sum / (float)cnt) : 0.f;
        s_avg[wave][lane] = avg;
    }
    __syncthreads();

    float pull_h   = 0.f;
    float push_row = 0.f;
    float nh       = 0.f;
    if (lane < NH) {
        #pragma unroll
        for (int j = 0; j < J; ++j) {
            if (mbits & (1u << j)) {
                const float d = vals[j] - avg;
                pull_h += d * d;
            }
        }
        nh = (cnt > 0) ? 1.f : 0.f;
        #pragma unroll
        for (int m = 0; m < NH; ++m) {
            const float d = avg - s_avg[wave][m];
            push_row += expf(-0.5f * d * d);
        }
    }

    // Reduce pull, push, num_humans across the 64-lane wave (lanes >= NH hold 0).
    float psum = pull_h, qsum = push_row, nsum = nh;
    #pragma unroll
    for (int off = 32; off > 0; off >>= 1) {
        psum += __shfl_down(psum, off);
        qsum += __shfl_down(qsum, off);
        nsum += __shfl_down(nsum, off);
    }
    if (lane == 0) {
        const float inv = 1.f / nsum;          // num_humans (reference divides unguarded)
        s_loss[wave] = psum * inv + qsum * inv * inv;
    }
    __syncthreads();

    if (threadIdx.x == 0) out[b] = s_loss[0] + s_loss[1];
}

extern "C" void kernel_launch(void* const* d_in, const int* in_sizes, int n_in,
                              void* d_out, int out_size, void* d_ws, size_t ws_size,
                              hipStream_t stream) {
    const float* tm0  = (const float*)d_in[0];
    const float* tm1  = (const float*)d_in[1];
    const int*   kps0 = (const int*)d_in[2];
    const int*   kps1 = (const int*)d_in[3];
    float*       out  = (float*)d_out;

    const int B = in_sizes[2] / (NH * 3 * J);   // 8
    ae_loss_kernel<<<B, 128, 0, stream>>>(tm0, tm1, kps0, kps1, out);
}